// Round 2
// 968.235 us; speedup vs baseline: 1.0934x; 1.0934x over previous
//
#include <hip/hip_runtime.h>

// ---------------------------------------------------------------------------
// KNNAttentionAggBeforeMLP: B=2 S=1024 DM=1024 H=16 HD=64 M=32
// Pipeline: LN1 -> QKV gemm(bf16 mfma) -> {mem-attn over M=32, causal flash}
//           -> c_proj gemm -> gate+residual+LN2 -> fc gemm+gelu -> proj gemm+res
// R1 changes (resubmitted R2 after infra failure; code audited, no OOB/hang):
//   memattn coalesced K-phase; GEMM BK=64 + XOR-swizzled LDS
//   (pre-swizzled global src, linear global_load_lds dest);
//   flash Vt write swizzle + heavy-tile-first ordering.
// ---------------------------------------------------------------------------

typedef short bf16x8 __attribute__((ext_vector_type(8)));
typedef float f32x4 __attribute__((ext_vector_type(4)));

__device__ __forceinline__ unsigned short f2b(float x) {   // fp32 -> bf16 RNE
  unsigned int u = __float_as_uint(x);
  u += 0x7fffu + ((u >> 16) & 1u);
  return (unsigned short)(u >> 16);
}
__device__ __forceinline__ float b2f(unsigned int bits16) {
  return __uint_as_float(bits16 << 16);
}
// async global->LDS, width 16B. LDS dest semantics: wave-uniform base + lane*16
// (lane0's pointer is the base; our mapping keeps lane l <-> base + 16*l).
__device__ __forceinline__ void async16(const void* g, void* l) {
  __builtin_amdgcn_global_load_lds((__attribute__((address_space(1))) void*)g,
                                   (__attribute__((address_space(3))) void*)l,
                                   16, 0, 0);
}

// ---------------------------------------------------------------------------
// Weight transpose + fp32->bf16 cast:  W[K][N] -> Wt[N][K]
// ---------------------------------------------------------------------------
__global__ __launch_bounds__(256) void transpose_cast_kernel(
    const float* __restrict__ W, unsigned short* __restrict__ Wt, int K, int N) {
  __shared__ float tile[32][33];
  int n0 = blockIdx.x * 32, k0 = blockIdx.y * 32;
  int tx = threadIdx.x, ty = threadIdx.y;  // 32 x 8
#pragma unroll
  for (int i = 0; i < 4; i++)
    tile[ty + 8 * i][tx] = W[(size_t)(k0 + ty + 8 * i) * N + n0 + tx];
  __syncthreads();
#pragma unroll
  for (int i = 0; i < 4; i++)
    Wt[(size_t)(n0 + ty + 8 * i) * K + k0 + tx] = f2b(tile[tx][ty + 8 * i]);
}

// ---------------------------------------------------------------------------
// LayerNorm (row=1024) + cast bf16
// ---------------------------------------------------------------------------
__global__ __launch_bounds__(256) void ln_cast_kernel(
    const float* __restrict__ x, const float* __restrict__ gw,
    const float* __restrict__ bw, unsigned short* __restrict__ out) {
  int row = blockIdx.x, t = threadIdx.x;
  size_t base = (size_t)row * 1024 + t * 4;
  float4 v = *(const float4*)(x + base);
  float s = v.x + v.y + v.z + v.w;
  float q = v.x * v.x + v.y * v.y + v.z * v.z + v.w * v.w;
#pragma unroll
  for (int off = 32; off; off >>= 1) {
    s += __shfl_xor(s, off);
    q += __shfl_xor(q, off);
  }
  __shared__ float red[8];
  int w = t >> 6, l = t & 63;
  if (l == 0) { red[w] = s; red[w + 4] = q; }
  __syncthreads();
  s = red[0] + red[1] + red[2] + red[3];
  q = red[4] + red[5] + red[6] + red[7];
  float mean = s * (1.0f / 1024.0f);
  float var = q * (1.0f / 1024.0f) - mean * mean;
  float rstd = rsqrtf(var + 1e-5f);
  float4 g4 = *(const float4*)(gw + t * 4);
  float4 b4 = *(const float4*)(bw + t * 4);
  out[base + 0] = f2b((v.x - mean) * rstd * g4.x + b4.x);
  out[base + 1] = f2b((v.y - mean) * rstd * g4.y + b4.y);
  out[base + 2] = f2b((v.z - mean) * rstd * g4.z + b4.z);
  out[base + 3] = f2b((v.w - mean) * rstd * g4.w + b4.w);
}

// ---------------------------------------------------------------------------
// bf16 MFMA GEMM: 256 thr (2x2 waves), BK=64, tile BM x BN.
// A[M][K] bf16, Bt[N][K] bf16 (pre-transposed). K % 64 == 0.
// LDS rows are 128B; XOR-swizzle (T2, guideline-4 form): logical 16B chunk c
// of row r is stored at chunk c ^ (r&7). global_load_lds dest stays linear;
// the swizzle is applied on the per-lane GLOBAL source column (rule 21) and
// on the ds_read offset. Read bank pattern: 4*(lk^(lq&7)) -> 2-way, free.
// MODE epilogues:
//  0: +bias -> bf16 | 1: +bias -> f32 | 2: +bias,gelu -> bf16 | 3: +bias+res -> f32
// ---------------------------------------------------------------------------
template <int BM, int BN, int MODE>
__global__ __launch_bounds__(256, 2) void gemm_bf16(
    const unsigned short* __restrict__ A, const unsigned short* __restrict__ Bt,
    const float* __restrict__ bias, const float* __restrict__ res,
    void* __restrict__ outp, int N, int K) {
  constexpr int SM = BM / 32, SN = BN / 32;  // 16x16 subtiles per wave
  __shared__ __align__(16) unsigned short At[BM * 64];
  __shared__ __align__(16) unsigned short Bs[BN * 64];
  const int t = threadIdx.x, w = t >> 6, l = t & 63;
  const int wm = w >> 1, wn = w & 1;
  const int lq = l & 15, lk = l >> 4;
  const int m0 = blockIdx.y * BM, n0 = blockIdx.x * BN;
  // staging: thread t -> row t>>3 (of 32 per pass), 16B chunk t&7.
  // source column pre-swizzled: chunk ^ (row&7)  (row&7 == (t>>3)&7, p*32%8==0)
  const int sr = t >> 3;
  const int scs = (t & 7) ^ (sr & 7);
  const unsigned short* Ag = A + (size_t)(m0 + sr) * K + scs * 8;
  const unsigned short* Bg = Bt + (size_t)(n0 + sr) * K + scs * 8;
  unsigned short* Al = &At[(size_t)t * 8];  // linear dest: wave base + lane*16
  unsigned short* Bl = &Bs[(size_t)t * 8];
  const int swr = (lq & 7) << 3;  // read-side ushort-offset swizzle
  f32x4 acc[SM][SN] = {};

  for (int k0 = 0; k0 < K; k0 += 64) {
#pragma unroll
    for (int p = 0; p < BM / 32; ++p)
      async16(Ag + (size_t)(p * 32) * K + k0, Al + p * 2048);
#pragma unroll
    for (int p = 0; p < BN / 32; ++p)
      async16(Bg + (size_t)(p * 32) * K + k0, Bl + p * 2048);
    __syncthreads();  // drains vmcnt (global_load_lds) per barrier semantics
#pragma unroll
    for (int kk = 0; kk < 2; ++kk) {
      const int koff = (kk * 32 + lk * 8) ^ swr;
      bf16x8 af[SM], bv[SN];
#pragma unroll
      for (int i = 0; i < SM; i++)
        af[i] = *(const bf16x8*)&At[(wm * (BM / 2) + i * 16 + lq) * 64 + koff];
#pragma unroll
      for (int j = 0; j < SN; j++)
        bv[j] = *(const bf16x8*)&Bs[(wn * (BN / 2) + j * 16 + lq) * 64 + koff];
#pragma unroll
      for (int i = 0; i < SM; i++)
#pragma unroll
        for (int j = 0; j < SN; j++)
          acc[i][j] = __builtin_amdgcn_mfma_f32_16x16x32_bf16(af[i], bv[j], acc[i][j], 0, 0, 0);
    }
    __syncthreads();
  }

#pragma unroll
  for (int i = 0; i < SM; i++) {
    int mrow = m0 + wm * (BM / 2) + i * 16 + lk * 4;  // C/D: row=quad*4+r
#pragma unroll
    for (int j = 0; j < SN; j++) {
      int ncol = n0 + wn * (BN / 2) + j * 16 + lq;    // C/D: col=lane&15
      float bval = bias[ncol];
#pragma unroll
      for (int r = 0; r < 4; r++) {
        size_t idx = (size_t)(mrow + r) * N + ncol;
        float v = acc[i][j][r] + bval;
        if (MODE == 0) {
          ((unsigned short*)outp)[idx] = f2b(v);
        } else if (MODE == 1) {
          ((float*)outp)[idx] = v;
        } else if (MODE == 2) {  // gelu_new (tanh approx)
          float u = v + 0.044715f * v * v * v;
          float e = __expf(1.5957691216057308f * u);  // 2*sqrt(2/pi)*u
          float th = 1.0f - 2.0f / (e + 1.0f);        // tanh via exp
          ((unsigned short*)outp)[idx] = f2b(0.5f * v * (1.0f + th));
        } else {
          ((float*)outp)[idx] = v + res[idx];
        }
      }
    }
  }
}

// ---------------------------------------------------------------------------
// Memory attention: one block per (b,s). softmax over M=32 per head, then
// weighted V sum. Streams this row's 256KB of mem_kv exactly once.
// K-phase is wave-parallel & coalesced: lane l owns d in [16l,16l+16);
// wave w handles m = 4w..4w+3; dots reduced via shfl_xor(1,2) and staged
// in padded LDS [16][33] (bank-conflict-free: bank=(h+m)%32).
// ---------------------------------------------------------------------------
__global__ __launch_bounds__(512) void memattn_kernel(
    const unsigned short* __restrict__ qkv, const float* __restrict__ memkv,
    float* __restrict__ out) {
  int bs = blockIdx.x, t = threadIdx.x;
  __shared__ float dotb[16 * 33];
  __shared__ float wsm[512];
  int w = t >> 6, l = t & 63;
  // q fragment: lane l holds q[l*16 .. l*16+16) (head l>>2), bf16 -> f32 regs
  const unsigned short* qp = qkv + (size_t)bs * 3072 + l * 16;
  bf16x8 qa = *(const bf16x8*)qp;
  bf16x8 qb = *(const bf16x8*)(qp + 8);
  float qreg[16];
#pragma unroll
  for (int i = 0; i < 8; i++) {
    qreg[i] = b2f((unsigned short)qa[i]);
    qreg[8 + i] = b2f((unsigned short)qb[i]);
  }
  const float* kbase = memkv + (size_t)bs * 65536 + (size_t)l * 16;
#pragma unroll
  for (int j = 0; j < 4; j++) {
    int m = w * 4 + j;
    const float* kp = kbase + (size_t)m * 2048;
    float dot = 0.0f;
#pragma unroll
    for (int d4 = 0; d4 < 4; d4++) {
      float4 kk = *(const float4*)(kp + d4 * 4);
      dot += kk.x * qreg[d4 * 4 + 0] + kk.y * qreg[d4 * 4 + 1] +
             kk.z * qreg[d4 * 4 + 2] + kk.w * qreg[d4 * 4 + 3];
    }
    dot += __shfl_xor(dot, 1);
    dot += __shfl_xor(dot, 2);  // lanes 4h..4h+3 all hold dot[m][h]
    if ((l & 3) == 0) dotb[(l >> 2) * 33 + m] = dot * 0.125f;  // 1/sqrt(64)
  }
  __syncthreads();
  {
    int h = t >> 5, m = t & 31;
    float d = dotb[h * 33 + m];
    float mx = d;
#pragma unroll
    for (int off = 1; off < 32; off <<= 1) mx = fmaxf(mx, __shfl_xor(mx, off));
    float e = __expf(d - mx);
    float sm = e;
#pragma unroll
    for (int off = 1; off < 32; off <<= 1) sm += __shfl_xor(sm, off);
    wsm[t] = e / sm;
  }
  __syncthreads();
  const float* vbase = memkv + (size_t)bs * 65536 + 1024;
#pragma unroll
  for (int rep = 0; rep < 2; ++rep) {
    int eidx = t + rep * 512;
    int he = eidx >> 6;
    const float* wrow = &wsm[he * 32];
    float acc = 0.0f;
#pragma unroll
    for (int mm = 0; mm < 32; ++mm) acc += wrow[mm] * vbase[(size_t)mm * 2048 + eidx];
    out[(size_t)bs * 1024 + eidx] = acc;
  }
}

// ---------------------------------------------------------------------------
// Causal flash attention, bf16 MFMA 16x16x32. Block = (b,h,qtile of 64 rows),
// 4 waves x 16 q-rows. KV chunks of 32 staged in LDS (V transposed with
// kv-column swizzle ^((d8&3)<<3): keeps 16B-aligned b128 reads, spreads the
// b16 transpose writes from 8-way to ~2-way bank conflict).
// Heavy tiles (qt=15: 32 chunks) dispatch first (LPT vs 16x imbalance).
// ---------------------------------------------------------------------------
__global__ __launch_bounds__(256) void flash_kernel(
    const unsigned short* __restrict__ qkv, unsigned short* __restrict__ out) {
  int blk = blockIdx.x;
  int qt = 15 - (blk & 15), bh = blk >> 4;  // heavy q-tiles first
  int b = bh >> 4, h = bh & 15;
  int t = threadIdx.x, w = t >> 6, l = t & 63;
  int lq = l & 15, lk = l >> 4;
  __shared__ __align__(16) unsigned short Kt[32 * 72];      // [kv32][d64+pad8]
  __shared__ __align__(16) unsigned short Vt[64 * 40];      // [d64][kv32+pad8], kv swizzled
  __shared__ __align__(16) unsigned short Pb[4][16 * 40];   // per-wave P [16][32+pad]

  const unsigned short* base = qkv + (size_t)b * 1024 * 3072;
  int qr0 = qt * 64 + w * 16;

  bf16x8 qf0 = *(const bf16x8*)(base + (size_t)(qr0 + lq) * 3072 + h * 64 + lk * 8);
  bf16x8 qf1 = *(const bf16x8*)(base + (size_t)(qr0 + lq) * 3072 + h * 64 + 32 + lk * 8);

  f32x4 o[4] = {};
  float mrow[4], lrow[4];
#pragma unroll
  for (int r = 0; r < 4; r++) { mrow[r] = -1e30f; lrow[r] = 0.0f; }

  int nch = (qt + 1) * 2;
  for (int c = 0; c < nch; ++c) {
    int kv0 = c * 32;
    {  // stage K chunk + V chunk (transposed, kv column swizzled by (d8&3)<<3)
      int rr = t >> 3, d8 = t & 7;
      const unsigned short* krow = base + (size_t)(kv0 + rr) * 3072 + 1024 + h * 64;
      *(bf16x8*)&Kt[rr * 72 + d8 * 8] = *(const bf16x8*)(krow + d8 * 8);
      bf16x8 v8 = *(const bf16x8*)(krow + 1024 + d8 * 8);
      int vc = rr ^ ((d8 & 3) << 3);
#pragma unroll
      for (int i = 0; i < 8; i++) Vt[(d8 * 8 + i) * 40 + vc] = (unsigned short)v8[i];
    }
    __syncthreads();

    // ---- scores + online softmax ----
    f32x4 sv[2];
#pragma unroll
    for (int j = 0; j < 2; j++) {
      if (kv0 + j * 16 <= qr0 + 15) {
        bf16x8 k0f = *(const bf16x8*)&Kt[(j * 16 + lq) * 72 + lk * 8];
        bf16x8 k1f = *(const bf16x8*)&Kt[(j * 16 + lq) * 72 + 32 + lk * 8];
        f32x4 s = {};
        s = __builtin_amdgcn_mfma_f32_16x16x32_bf16(qf0, k0f, s, 0, 0, 0);
        s = __builtin_amdgcn_mfma_f32_16x16x32_bf16(qf1, k1f, s, 0, 0, 0);
#pragma unroll
        for (int r = 0; r < 4; r++) {
          float x = s[r] * 0.125f;
          int qrow = qr0 + lk * 4 + r;
          int kvg = kv0 + j * 16 + lq;
          if (kvg > qrow) x = -1e30f;
          s[r] = x;
        }
        sv[j] = s;
      } else {
        sv[j] = (f32x4){-1e30f, -1e30f, -1e30f, -1e30f};
      }
    }
#pragma unroll
    for (int r = 0; r < 4; r++) {
      float mnew = fmaxf(sv[0][r], sv[1][r]);
#pragma unroll
      for (int off = 1; off < 16; off <<= 1) mnew = fmaxf(mnew, __shfl_xor(mnew, off));
      mnew = fmaxf(mnew, mrow[r]);
      float a = __expf(mrow[r] - mnew);
      float e0 = __expf(sv[0][r] - mnew);
      float e1 = __expf(sv[1][r] - mnew);
      float rs = e0 + e1;
#pragma unroll
      for (int off = 1; off < 16; off <<= 1) rs += __shfl_xor(rs, off);
      lrow[r] = lrow[r] * a + rs;
      mrow[r] = mnew;
      o[0][r] *= a; o[1][r] *= a; o[2][r] *= a; o[3][r] *= a;
      Pb[w][(lk * 4 + r) * 40 + lq] = f2b(e0);
      Pb[w][(lk * 4 + r) * 40 + 16 + lq] = f2b(e1);
    }
    __syncthreads();

    // ---- PV ----
    if (kv0 <= qr0 + 15) {
      bf16x8 pf = *(const bf16x8*)&Pb[w][lq * 40 + lk * 8];  // A-layout
#pragma unroll
      for (int dt = 0; dt < 4; dt++) {
        int s = (dt * 2 + (lq >> 3)) & 3;  // d8&3 of row d=dt*16+lq
        bf16x8 vf = *(const bf16x8*)&Vt[(dt * 16 + lq) * 40 + ((lk ^ s) << 3)];
        o[dt] = __builtin_amdgcn_mfma_f32_16x16x32_bf16(pf, vf, o[dt], 0, 0, 0);
      }
    }
    __syncthreads();
  }

  unsigned short* op = out + (size_t)b * 1024 * 1024 + h * 64;
#pragma unroll
  for (int dt = 0; dt < 4; dt++)
#pragma unroll
    for (int r = 0; r < 4; r++) {
      float v = o[dt][r] / lrow[r];
      op[(size_t)(qr0 + lk * 4 + r) * 1024 + dt * 16 + lq] = f2b(v);
    }
}

// ---------------------------------------------------------------------------
// attn_out = (1-g)*std_proj + g*mem_attn + residual ; store fp32 (residual2)
// then LN2 -> bf16
// ---------------------------------------------------------------------------
__global__ __launch_bounds__(256) void combine_ln2_kernel(
    const float* __restrict__ stdp, const float* __restrict__ mem,
    const float* __restrict__ resid, const float* __restrict__ gval,
    const float* __restrict__ gw, const float* __restrict__ bw,
    float* __restrict__ hmid, unsigned short* __restrict__ h2) {
  int row = blockIdx.x, t = threadIdx.x;
  float g = gval[0];
  size_t base = (size_t)row * 1024 + t * 4;
  float4 a = *(const float4*)(stdp + base);
  float4 m4 = *(const float4*)(mem + base);
  float4 r4 = *(const float4*)(resid + base);
  float4 hv;
  hv.x = (1.0f - g) * a.x + g * m4.x + r4.x;
  hv.y = (1.0f - g) * a.y + g * m4.y + r4.y;
  hv.z = (1.0f - g) * a.z + g * m4.z + r4.z;
  hv.w = (1.0f - g) * a.w + g * m4.w + r4.w;
  *(float4*)(hmid + base) = hv;
  float s = hv.x + hv.y + hv.z + hv.w;
  float q = hv.x * hv.x + hv.y * hv.y + hv.z * hv.z + hv.w * hv.w;
#pragma unroll
  for (int off = 32; off; off >>= 1) {
    s += __shfl_xor(s, off);
    q += __shfl_xor(q, off);
  }
  __shared__ float red[8];
  int w = t >> 6, l = t & 63;
  if (l == 0) { red[w] = s; red[w + 4] = q; }
  __syncthreads();
  s = red[0] + red[1] + red[2] + red[3];
  q = red[4] + red[5] + red[6] + red[7];
  float mean = s * (1.0f / 1024.0f);
  float var = q * (1.0f / 1024.0f) - mean * mean;
  float rstd = rsqrtf(var + 1e-5f);
  float4 g4 = *(const float4*)(gw + t * 4);
  float4 b4 = *(const float4*)(bw + t * 4);
  h2[base + 0] = f2b((hv.x - mean) * rstd * g4.x + b4.x);
  h2[base + 1] = f2b((hv.y - mean) * rstd * g4.y + b4.y);
  h2[base + 2] = f2b((hv.z - mean) * rstd * g4.z + b4.z);
  h2[base + 3] = f2b((hv.w - mean) * rstd * g4.w + b4.w);
}

// ---------------------------------------------------------------------------
extern "C" void kernel_launch(void* const* d_in, const int* in_sizes, int n_in,
                              void* d_out, int out_size, void* d_ws, size_t ws_size,
                              hipStream_t stream) {
  const float* prev = (const float*)d_in[0];
  const float* memkv = (const float*)d_in[1];
  const float* gval = (const float*)d_in[2];
  const float* ln1g = (const float*)d_in[3];
  const float* ln1b = (const float*)d_in[4];
  const float* attw = (const float*)d_in[5];
  const float* attb = (const float*)d_in[6];
  const float* cpw = (const float*)d_in[7];
  const float* cpb = (const float*)d_in[8];
  const float* ln2g = (const float*)d_in[9];
  const float* ln2b = (const float*)d_in[10];
  const float* fcw = (const float*)d_in[11];
  const float* fcb = (const float*)d_in[12];
  const float* pjw = (const float*)d_in[13];
  const float* pjb = (const float*)d_in[14];

  char* ws = (char*)d_ws;
  size_t off = 0;
  unsigned short* wqkv_t = (unsigned short*)(ws + off); off += (size_t)3072 * 1024 * 2;
  unsigned short* wcp_t  = (unsigned short*)(ws + off); off += (size_t)1024 * 1024 * 2;
  unsigned short* wfc_t  = (unsigned short*)(ws + off); off += (size_t)4096 * 1024 * 2;
  unsigned short* wpj_t  = (unsigned short*)(ws + off); off += (size_t)1024 * 4096 * 2;
  unsigned short* h_bf   = (unsigned short*)(ws + off); off += (size_t)2048 * 1024 * 2;
  unsigned short* qkv_bf = (unsigned short*)(ws + off); off += (size_t)2048 * 3072 * 2;
  unsigned short* satt_bf= (unsigned short*)(ws + off); off += (size_t)2048 * 1024 * 2;
  unsigned short* h2_bf  = (unsigned short*)(ws + off); off += (size_t)2048 * 1024 * 2;
  float* matt  = (float*)(ws + off); off += (size_t)2048 * 1024 * 4;
  float* sproj = (float*)(ws + off); off += (size_t)2048 * 1024 * 4;
  float* hmid  = (float*)(ws + off); off += (size_t)2048 * 1024 * 4;
  unsigned short* ff1_bf = (unsigned short*)(ws + off); off += (size_t)2048 * 4096 * 2;

  dim3 tb(32, 8);
  transpose_cast_kernel<<<dim3(3072 / 32, 1024 / 32), tb, 0, stream>>>(attw, wqkv_t, 1024, 3072);
  transpose_cast_kernel<<<dim3(1024 / 32, 1024 / 32), tb, 0, stream>>>(cpw, wcp_t, 1024, 1024);
  transpose_cast_kernel<<<dim3(4096 / 32, 1024 / 32), tb, 0, stream>>>(fcw, wfc_t, 1024, 4096);
  transpose_cast_kernel<<<dim3(1024 / 32, 4096 / 32), tb, 0, stream>>>(pjw, wpj_t, 4096, 1024);

  ln_cast_kernel<<<2048, 256, 0, stream>>>(prev, ln1g, ln1b, h_bf);

  // qkv = h @ c_attn_w + b   [2048,1024]x[1024,3072] -> bf16
  gemm_bf16<128, 128, 0><<<dim3(24, 16), 256, 0, stream>>>(h_bf, wqkv_t, attb, nullptr, qkv_bf, 3072, 1024);

  memattn_kernel<<<2048, 512, 0, stream>>>(qkv_bf, memkv, matt);
  flash_kernel<<<512, 256, 0, stream>>>(qkv_bf, satt_bf);

  // std_proj = satt @ c_proj_w + b  -> f32
  gemm_bf16<128, 64, 1><<<dim3(16, 16), 256, 0, stream>>>(satt_bf, wcp_t, cpb, nullptr, sproj, 1024, 1024);

  combine_ln2_kernel<<<2048, 256, 0, stream>>>(sproj, matt, prev, gval, ln2g, ln2b, hmid, h2_bf);

  // ff1 = gelu(h2 @ fc_w + b)  [2048,1024]x[1024,4096] -> bf16
  gemm_bf16<128, 128, 2><<<dim3(32, 16), 256, 0, stream>>>(h2_bf, wfc_t, fcb, nullptr, ff1_bf, 4096, 1024);

  // out = ff1 @ proj_w + b + hmid  [2048,4096]x[4096,1024] -> f32
  gemm_bf16<128, 64, 3><<<dim3(16, 16), 256, 0, stream>>>(ff1_bf, wpj_t, pjb, hmid, (float*)d_out, 1024, 4096);
}

// Round 3
// 907.100 us; speedup vs baseline: 1.1671x; 1.0674x over previous
//
#include <hip/hip_runtime.h>

// ---------------------------------------------------------------------------
// KNNAttentionAggBeforeMLP: B=2 S=1024 DM=1024 H=16 HD=64 M=32
// R3 changes:
//   * GEMM: double-buffered LDS (T3-minimum 2-phase: issue next-tile
//     global_load_lds BEFORE computing current tile; one barrier per K-iter)
//   * c_proj / proj GEMMs retiled 128x64 -> 64x64 (grid 256 -> 512 blocks,
//     4 blocks/CU) to fix 1-block/CU grid starvation
//   * memattn + flash fused into one dispatch (flash blocks first) so the
//     537MB memattn HBM stream overlaps flash MFMA compute
// ---------------------------------------------------------------------------

typedef short bf16x8 __attribute__((ext_vector_type(8)));
typedef float f32x4 __attribute__((ext_vector_type(4)));

__device__ __forceinline__ unsigned short f2b(float x) {   // fp32 -> bf16 RNE
  unsigned int u = __float_as_uint(x);
  u += 0x7fffu + ((u >> 16) & 1u);
  return (unsigned short)(u >> 16);
}
__device__ __forceinline__ float b2f(unsigned int bits16) {
  return __uint_as_float(bits16 << 16);
}
// async global->LDS, width 16B. LDS dest semantics: wave-uniform base + lane*16.
__device__ __forceinline__ void async16(const void* g, void* l) {
  __builtin_amdgcn_global_load_lds((__attribute__((address_space(1))) void*)g,
                                   (__attribute__((address_space(3))) void*)l,
                                   16, 0, 0);
}

// ---------------------------------------------------------------------------
// Weight transpose + fp32->bf16 cast:  W[K][N] -> Wt[N][K]
// ---------------------------------------------------------------------------
__global__ __launch_bounds__(256) void transpose_cast_kernel(
    const float* __restrict__ W, unsigned short* __restrict__ Wt, int K, int N) {
  __shared__ float tile[32][33];
  int n0 = blockIdx.x * 32, k0 = blockIdx.y * 32;
  int tx = threadIdx.x, ty = threadIdx.y;  // 32 x 8
#pragma unroll
  for (int i = 0; i < 4; i++)
    tile[ty + 8 * i][tx] = W[(size_t)(k0 + ty + 8 * i) * N + n0 + tx];
  __syncthreads();
#pragma unroll
  for (int i = 0; i < 4; i++)
    Wt[(size_t)(n0 + ty + 8 * i) * K + k0 + tx] = f2b(tile[tx][ty + 8 * i]);
}

// ---------------------------------------------------------------------------
// LayerNorm (row=1024) + cast bf16
// ---------------------------------------------------------------------------
__global__ __launch_bounds__(256) void ln_cast_kernel(
    const float* __restrict__ x, const float* __restrict__ gw,
    const float* __restrict__ bw, unsigned short* __restrict__ out) {
  int row = blockIdx.x, t = threadIdx.x;
  size_t base = (size_t)row * 1024 + t * 4;
  float4 v = *(const float4*)(x + base);
  float s = v.x + v.y + v.z + v.w;
  float q = v.x * v.x + v.y * v.y + v.z * v.z + v.w * v.w;
#pragma unroll
  for (int off = 32; off; off >>= 1) {
    s += __shfl_xor(s, off);
    q += __shfl_xor(q, off);
  }
  __shared__ float red[8];
  int w = t >> 6, l = t & 63;
  if (l == 0) { red[w] = s; red[w + 4] = q; }
  __syncthreads();
  s = red[0] + red[1] + red[2] + red[3];
  q = red[4] + red[5] + red[6] + red[7];
  float mean = s * (1.0f / 1024.0f);
  float var = q * (1.0f / 1024.0f) - mean * mean;
  float rstd = rsqrtf(var + 1e-5f);
  float4 g4 = *(const float4*)(gw + t * 4);
  float4 b4 = *(const float4*)(bw + t * 4);
  out[base + 0] = f2b((v.x - mean) * rstd * g4.x + b4.x);
  out[base + 1] = f2b((v.y - mean) * rstd * g4.y + b4.y);
  out[base + 2] = f2b((v.z - mean) * rstd * g4.z + b4.z);
  out[base + 3] = f2b((v.w - mean) * rstd * g4.w + b4.w);
}

// ---------------------------------------------------------------------------
// bf16 MFMA GEMM: 256 thr (2x2 waves), BK=64, tile BM x BN, DOUBLE-BUFFERED.
// A[M][K] bf16, Bt[N][K] bf16 (pre-transposed). K % 64 == 0.
// XOR-swizzled LDS (pre-swizzled global source, linear global_load_lds dest;
// read offset ^((lq&7)<<3)). Per K-iter: issue next-tile stage, compute
// current tile, one __syncthreads (drains vmcnt+lgkmcnt) -> overlap.
// MODE: 0:+bias->bf16 | 1:+bias->f32 | 2:+bias,gelu->bf16 | 3:+bias+res->f32
// MINW: min waves/EU (occupancy hint; =blocks/CU for 256-thr blocks)
// ---------------------------------------------------------------------------
template <int BM, int BN, int MODE, int MINW>
__global__ __launch_bounds__(256, MINW) void gemm_bf16(
    const unsigned short* __restrict__ A, const unsigned short* __restrict__ Bt,
    const float* __restrict__ bias, const float* __restrict__ res,
    void* __restrict__ outp, int N, int K) {
  constexpr int SM = BM / 32, SN = BN / 32;  // 16x16 subtiles per wave
  __shared__ __align__(16) unsigned short At[2][BM * 64];
  __shared__ __align__(16) unsigned short Bs[2][BN * 64];
  const int t = threadIdx.x, w = t >> 6, l = t & 63;
  const int wm = w >> 1, wn = w & 1;
  const int lq = l & 15, lk = l >> 4;
  const int m0 = blockIdx.y * BM, n0 = blockIdx.x * BN;
  // staging: thread t -> row t>>3 (of 32 per pass), 16B chunk t&7.
  // source column pre-swizzled: chunk ^ (row&7)
  const int sr = t >> 3;
  const int scs = (t & 7) ^ (sr & 7);
  const unsigned short* Ag = A + (size_t)(m0 + sr) * K + scs * 8;
  const unsigned short* Bg = Bt + (size_t)(n0 + sr) * K + scs * 8;
  const int swr = (lq & 7) << 3;  // read-side ushort-offset swizzle
  f32x4 acc[SM][SN] = {};
  const int nt = K >> 6;

  auto stage = [&](int buf, int tt) {
    const int k0s = tt << 6;
#pragma unroll
    for (int p = 0; p < BM / 32; ++p)
      async16(Ag + (size_t)(p * 32) * K + k0s, &At[buf][t * 8 + p * 2048]);
#pragma unroll
    for (int p = 0; p < BN / 32; ++p)
      async16(Bg + (size_t)(p * 32) * K + k0s, &Bs[buf][t * 8 + p * 2048]);
  };

  stage(0, 0);
  __syncthreads();  // buf0 ready
  int cur = 0;
  for (int tt = 0; tt < nt; ++tt) {
    if (tt + 1 < nt) stage(cur ^ 1, tt + 1);  // loads in flight during compute
#pragma unroll
    for (int kk = 0; kk < 2; ++kk) {
      const int koff = (kk * 32 + lk * 8) ^ swr;
      bf16x8 af[SM], bv[SN];
#pragma unroll
      for (int i = 0; i < SM; i++)
        af[i] = *(const bf16x8*)&At[cur][(wm * (BM / 2) + i * 16 + lq) * 64 + koff];
#pragma unroll
      for (int j = 0; j < SN; j++)
        bv[j] = *(const bf16x8*)&Bs[cur][(wn * (BN / 2) + j * 16 + lq) * 64 + koff];
#pragma unroll
      for (int i = 0; i < SM; i++)
#pragma unroll
        for (int j = 0; j < SN; j++)
          acc[i][j] = __builtin_amdgcn_mfma_f32_16x16x32_bf16(af[i], bv[j], acc[i][j], 0, 0, 0);
    }
    __syncthreads();  // drains stage vmcnt + all reads of cur done
    cur ^= 1;
  }

#pragma unroll
  for (int i = 0; i < SM; i++) {
    int mrow = m0 + wm * (BM / 2) + i * 16 + lk * 4;  // C/D: row=quad*4+r
#pragma unroll
    for (int j = 0; j < SN; j++) {
      int ncol = n0 + wn * (BN / 2) + j * 16 + lq;    // C/D: col=lane&15
      float bval = bias[ncol];
#pragma unroll
      for (int r = 0; r < 4; r++) {
        size_t idx = (size_t)(mrow + r) * N + ncol;
        float v = acc[i][j][r] + bval;
        if (MODE == 0) {
          ((unsigned short*)outp)[idx] = f2b(v);
        } else if (MODE == 1) {
          ((float*)outp)[idx] = v;
        } else if (MODE == 2) {  // gelu_new (tanh approx)
          float u = v + 0.044715f * v * v * v;
          float e = __expf(1.5957691216057308f * u);  // 2*sqrt(2/pi)*u
          float th = 1.0f - 2.0f / (e + 1.0f);        // tanh via exp
          ((unsigned short*)outp)[idx] = f2b(0.5f * v * (1.0f + th));
        } else {
          ((float*)outp)[idx] = v + res[idx];
        }
      }
    }
  }
}

// ---------------------------------------------------------------------------
// Fused attention dispatch, 256 threads/block:
//   blocks [0,512)    : causal flash attention (dispatched first -> compute
//                       waves resident early)
//   blocks [512,2560) : memory attention (pure HBM stream, fills mem pipes
//                       while flash occupies MFMA)
// ---------------------------------------------------------------------------
__global__ __launch_bounds__(256) void attn_fused_kernel(
    const unsigned short* __restrict__ qkv, const float* __restrict__ memkv,
    unsigned short* __restrict__ satt, float* __restrict__ matt) {
  __shared__ __align__(16) unsigned short smem[7424];  // 14.5 KB union
  int t = threadIdx.x;

  if (blockIdx.x < 512) {
    // ================= causal flash =================
    unsigned short* Kt = smem;          // [32][72]
    unsigned short* Vt = smem + 2304;   // [64][40], kv col swizzled
    unsigned short* Pb = smem + 4864;   // [4][16*40]
    int blk = blockIdx.x;
    int qt = 15 - (blk & 15), bh = blk >> 4;  // heavy q-tiles first
    int b = bh >> 4, h = bh & 15;
    int w = t >> 6, l = t & 63;
    int lq = l & 15, lk = l >> 4;

    const unsigned short* base = qkv + (size_t)b * 1024 * 3072;
    int qr0 = qt * 64 + w * 16;

    bf16x8 qf0 = *(const bf16x8*)(base + (size_t)(qr0 + lq) * 3072 + h * 64 + lk * 8);
    bf16x8 qf1 = *(const bf16x8*)(base + (size_t)(qr0 + lq) * 3072 + h * 64 + 32 + lk * 8);

    f32x4 o[4] = {};
    float mrow[4], lrow[4];
#pragma unroll
    for (int r = 0; r < 4; r++) { mrow[r] = -1e30f; lrow[r] = 0.0f; }

    int nch = (qt + 1) * 2;
    for (int c = 0; c < nch; ++c) {
      int kv0 = c * 32;
      {  // stage K chunk + V chunk (transposed, kv column swizzled by (d8&3)<<3)
        int rr = t >> 3, d8 = t & 7;
        const unsigned short* krow = base + (size_t)(kv0 + rr) * 3072 + 1024 + h * 64;
        *(bf16x8*)&Kt[rr * 72 + d8 * 8] = *(const bf16x8*)(krow + d8 * 8);
        bf16x8 v8 = *(const bf16x8*)(krow + 1024 + d8 * 8);
        int vc = rr ^ ((d8 & 3) << 3);
#pragma unroll
        for (int i = 0; i < 8; i++) Vt[(d8 * 8 + i) * 40 + vc] = (unsigned short)v8[i];
      }
      __syncthreads();

      // ---- scores + online softmax ----
      f32x4 sv[2];
#pragma unroll
      for (int j = 0; j < 2; j++) {
        if (kv0 + j * 16 <= qr0 + 15) {
          bf16x8 k0f = *(const bf16x8*)&Kt[(j * 16 + lq) * 72 + lk * 8];
          bf16x8 k1f = *(const bf16x8*)&Kt[(j * 16 + lq) * 72 + 32 + lk * 8];
          f32x4 s = {};
          s = __builtin_amdgcn_mfma_f32_16x16x32_bf16(qf0, k0f, s, 0, 0, 0);
          s = __builtin_amdgcn_mfma_f32_16x16x32_bf16(qf1, k1f, s, 0, 0, 0);
#pragma unroll
          for (int r = 0; r < 4; r++) {
            float x = s[r] * 0.125f;
            int qrow = qr0 + lk * 4 + r;
            int kvg = kv0 + j * 16 + lq;
            if (kvg > qrow) x = -1e30f;
            s[r] = x;
          }
          sv[j] = s;
        } else {
          sv[j] = (f32x4){-1e30f, -1e30f, -1e30f, -1e30f};
        }
      }
#pragma unroll
      for (int r = 0; r < 4; r++) {
        float mnew = fmaxf(sv[0][r], sv[1][r]);
#pragma unroll
        for (int off = 1; off < 16; off <<= 1) mnew = fmaxf(mnew, __shfl_xor(mnew, off));
        mnew = fmaxf(mnew, mrow[r]);
        float a = __expf(mrow[r] - mnew);
        float e0 = __expf(sv[0][r] - mnew);
        float e1 = __expf(sv[1][r] - mnew);
        float rs = e0 + e1;
#pragma unroll
        for (int off = 1; off < 16; off <<= 1) rs += __shfl_xor(rs, off);
        lrow[r] = lrow[r] * a + rs;
        mrow[r] = mnew;
        o[0][r] *= a; o[1][r] *= a; o[2][r] *= a; o[3][r] *= a;
        Pb[w * 640 + (lk * 4 + r) * 40 + lq] = f2b(e0);
        Pb[w * 640 + (lk * 4 + r) * 40 + 16 + lq] = f2b(e1);
      }
      __syncthreads();

      // ---- PV ----
      if (kv0 <= qr0 + 15) {
        bf16x8 pf = *(const bf16x8*)&Pb[w * 640 + lq * 40 + lk * 8];  // A-layout
#pragma unroll
        for (int dt = 0; dt < 4; dt++) {
          int s = (dt * 2 + (lq >> 3)) & 3;  // d8&3 of row d=dt*16+lq
          bf16x8 vf = *(const bf16x8*)&Vt[(dt * 16 + lq) * 40 + ((lk ^ s) << 3)];
          o[dt] = __builtin_amdgcn_mfma_f32_16x16x32_bf16(pf, vf, o[dt], 0, 0, 0);
        }
      }
      __syncthreads();
    }

    unsigned short* op = satt + (size_t)b * 1024 * 1024 + h * 64;
#pragma unroll
    for (int dt = 0; dt < 4; dt++)
#pragma unroll
      for (int r = 0; r < 4; r++) {
        float v = o[dt][r] / lrow[r];
        op[(size_t)(qr0 + lk * 4 + r) * 1024 + dt * 16 + lq] = f2b(v);
      }
  } else {
    // ================= memory attention (256 thr) =================
    float* dotb = (float*)smem;          // [16][33]
    float* wsm = (float*)smem + 528;     // [512]
    int bs = blockIdx.x - 512;
    int w = t >> 6, l = t & 63;
    // q fragment: lane l holds q[l*16 .. l*16+16) (head l>>2), bf16 -> f32
    const unsigned short* qp = qkv + (size_t)bs * 3072 + l * 16;
    bf16x8 qa = *(const bf16x8*)qp;
    bf16x8 qb = *(const bf16x8*)(qp + 8);
    float qreg[16];
#pragma unroll
    for (int i = 0; i < 8; i++) {
      qreg[i] = b2f((unsigned short)qa[i]);
      qreg[8 + i] = b2f((unsigned short)qb[i]);
    }
    const float* kbase = memkv + (size_t)bs * 65536 + (size_t)l * 16;
#pragma unroll
    for (int j = 0; j < 8; j++) {  // wave w handles m = 8w .. 8w+7
      int m = w * 8 + j;
      const float* kp = kbase + (size_t)m * 2048;
      float dot = 0.0f;
#pragma unroll
      for (int d4 = 0; d4 < 4; d4++) {
        float4 kk = *(const float4*)(kp + d4 * 4);
        dot += kk.x * qreg[d4 * 4 + 0] + kk.y * qreg[d4 * 4 + 1] +
               kk.z * qreg[d4 * 4 + 2] + kk.w * qreg[d4 * 4 + 3];
      }
      dot += __shfl_xor(dot, 1);
      dot += __shfl_xor(dot, 2);  // lanes 4h..4h+3 all hold dot[m][h]
      if ((l & 3) == 0) dotb[(l >> 2) * 33 + m] = dot * 0.125f;  // 1/sqrt(64)
    }
    __syncthreads();
#pragma unroll
    for (int rep = 0; rep < 2; ++rep) {
      int idx = t + rep * 256;  // (h,m): 32 consecutive lanes share h
      int h = idx >> 5, m = idx & 31;
      float d = dotb[h * 33 + m];
      float mx = d;
#pragma unroll
      for (int off = 1; off < 32; off <<= 1) mx = fmaxf(mx, __shfl_xor(mx, off));
      float e = __expf(d - mx);
      float sm = e;
#pragma unroll
      for (int off = 1; off < 32; off <<= 1) sm += __shfl_xor(sm, off);
      wsm[idx] = e / sm;
    }
    __syncthreads();
    const float* vbase = memkv + (size_t)bs * 65536 + 1024;
#pragma unroll
    for (int rep = 0; rep < 4; ++rep) {
      int eidx = t + rep * 256;
      int he = eidx >> 6;
      const float* wrow = &wsm[he * 32];
      float acc = 0.0f;
#pragma unroll
      for (int mm = 0; mm < 32; ++mm) acc += wrow[mm] * vbase[(size_t)mm * 2048 + eidx];
      matt[(size_t)bs * 1024 + eidx] = acc;
    }
  }
}

// ---------------------------------------------------------------------------
// attn_out = (1-g)*std_proj + g*mem_attn + residual ; store fp32 (residual2)
// then LN2 -> bf16
// ---------------------------------------------------------------------------
__global__ __launch_bounds__(256) void combine_ln2_kernel(
    const float* __restrict__ stdp, const float* __restrict__ mem,
    const float* __restrict__ resid, const float* __restrict__ gval,
    const float* __restrict__ gw, const float* __restrict__ bw,
    float* __restrict__ hmid, unsigned short* __restrict__ h2) {
  int row = blockIdx.x, t = threadIdx.x;
  float g = gval[0];
  size_t base = (size_t)row * 1024 + t * 4;
  float4 a = *(const float4*)(stdp + base);
  float4 m4 = *(const float4*)(mem + base);
  float4 r4 = *(const float4*)(resid + base);
  float4 hv;
  hv.x = (1.0f - g) * a.x + g * m4.x + r4.x;
  hv.y = (1.0f - g) * a.y + g * m4.y + r4.y;
  hv.z = (1.0f - g) * a.z + g * m4.z + r4.z;
  hv.w = (1.0f - g) * a.w + g * m4.w + r4.w;
  *(float4*)(hmid + base) = hv;
  float s = hv.x + hv.y + hv.z + hv.w;
  float q = hv.x * hv.x + hv.y * hv.y + hv.z * hv.z + hv.w * hv.w;
#pragma unroll
  for (int off = 32; off; off >>= 1) {
    s += __shfl_xor(s, off);
    q += __shfl_xor(q, off);
  }
  __shared__ float red[8];
  int w = t >> 6, l = t & 63;
  if (l == 0) { red[w] = s; red[w + 4] = q; }
  __syncthreads();
  s = red[0] + red[1] + red[2] + red[3];
  q = red[4] + red[5] + red[6] + red[7];
  float mean = s * (1.0f / 1024.0f);
  float var = q * (1.0f / 1024.0f) - mean * mean;
  float rstd = rsqrtf(var + 1e-5f);
  float4 g4 = *(const float4*)(gw + t * 4);
  float4 b4 = *(const float4*)(bw + t * 4);
  h2[base + 0] = f2b((hv.x - mean) * rstd * g4.x + b4.x);
  h2[base + 1] = f2b((hv.y - mean) * rstd * g4.y + b4.y);
  h2[base + 2] = f2b((hv.z - mean) * rstd * g4.z + b4.z);
  h2[base + 3] = f2b((hv.w - mean) * rstd * g4.w + b4.w);
}

// ---------------------------------------------------------------------------
extern "C" void kernel_launch(void* const* d_in, const int* in_sizes, int n_in,
                              void* d_out, int out_size, void* d_ws, size_t ws_size,
                              hipStream_t stream) {
  const float* prev = (const float*)d_in[0];
  const float* memkv = (const float*)d_in[1];
  const float* gval = (const float*)d_in[2];
  const float* ln1g = (const float*)d_in[3];
  const float* ln1b = (const float*)d_in[4];
  const float* attw = (const float*)d_in[5];
  const float* attb = (const float*)d_in[6];
  const float* cpw = (const float*)d_in[7];
  const float* cpb = (const float*)d_in[8];
  const float* ln2g = (const float*)d_in[9];
  const float* ln2b = (const float*)d_in[10];
  const float* fcw = (const float*)d_in[11];
  const float* fcb = (const float*)d_in[12];
  const float* pjw = (const float*)d_in[13];
  const float* pjb = (const float*)d_in[14];

  char* ws = (char*)d_ws;
  size_t off = 0;
  unsigned short* wqkv_t = (unsigned short*)(ws + off); off += (size_t)3072 * 1024 * 2;
  unsigned short* wcp_t  = (unsigned short*)(ws + off); off += (size_t)1024 * 1024 * 2;
  unsigned short* wfc_t  = (unsigned short*)(ws + off); off += (size_t)4096 * 1024 * 2;
  unsigned short* wpj_t  = (unsigned short*)(ws + off); off += (size_t)1024 * 4096 * 2;
  unsigned short* h_bf   = (unsigned short*)(ws + off); off += (size_t)2048 * 1024 * 2;
  unsigned short* qkv_bf = (unsigned short*)(ws + off); off += (size_t)2048 * 3072 * 2;
  unsigned short* satt_bf= (unsigned short*)(ws + off); off += (size_t)2048 * 1024 * 2;
  unsigned short* h2_bf  = (unsigned short*)(ws + off); off += (size_t)2048 * 1024 * 2;
  float* matt  = (float*)(ws + off); off += (size_t)2048 * 1024 * 4;
  float* sproj = (float*)(ws + off); off += (size_t)2048 * 1024 * 4;
  float* hmid  = (float*)(ws + off); off += (size_t)2048 * 1024 * 4;
  unsigned short* ff1_bf = (unsigned short*)(ws + off); off += (size_t)2048 * 4096 * 2;

  dim3 tb(32, 8);
  transpose_cast_kernel<<<dim3(3072 / 32, 1024 / 32), tb, 0, stream>>>(attw, wqkv_t, 1024, 3072);
  transpose_cast_kernel<<<dim3(1024 / 32, 1024 / 32), tb, 0, stream>>>(cpw, wcp_t, 1024, 1024);
  transpose_cast_kernel<<<dim3(4096 / 32, 1024 / 32), tb, 0, stream>>>(fcw, wfc_t, 1024, 4096);
  transpose_cast_kernel<<<dim3(1024 / 32, 4096 / 32), tb, 0, stream>>>(pjw, wpj_t, 4096, 1024);

  ln_cast_kernel<<<2048, 256, 0, stream>>>(prev, ln1g, ln1b, h_bf);

  // qkv = h @ c_attn_w + b   [2048,1024]x[1024,3072] -> bf16
  gemm_bf16<128, 128, 0, 2><<<dim3(24, 16), 256, 0, stream>>>(h_bf, wqkv_t, attb, nullptr, qkv_bf, 3072, 1024);

  // fused: flash (512 blocks) + memattn (2048 blocks)
  attn_fused_kernel<<<2560, 256, 0, stream>>>(qkv_bf, memkv, satt_bf, matt);

  // std_proj = satt @ c_proj_w + b  -> f32   (64x64 tile: 512 blocks)
  gemm_bf16<64, 64, 1, 4><<<dim3(16, 32), 256, 0, stream>>>(satt_bf, wcp_t, cpb, nullptr, sproj, 1024, 1024);

  combine_ln2_kernel<<<2048, 256, 0, stream>>>(sproj, matt, prev, gval, ln2g, ln2b, hmid, h2_bf);

  // ff1 = gelu(h2 @ fc_w + b)  [2048,1024]x[1024,4096] -> bf16
  gemm_bf16<128, 128, 2, 2><<<dim3(32, 16), 256, 0, stream>>>(h2_bf, wfc_t, fcb, nullptr, ff1_bf, 4096, 1024);

  // out = ff1 @ proj_w + b + hmid  [2048,4096]x[4096,1024] -> f32  (64x64: 512 blocks)
  gemm_bf16<64, 64, 3, 4><<<dim3(16, 32), 256, 0, stream>>>(ff1_bf, wpj_t, pjb, hmid, (float*)d_out, 1024, 4096);
}